// Round 7
// baseline (128.422 us; speedup 1.0000x reference)
//
#include <hip/hip_runtime.h>

#define BATCH 16
#define NUM_HEADS 32
#define NUM_KV 8
#define GQ 4            // query heads per kv head
#define HD 128
#define PAGE 256        // cache block size
#define MAXB 8
#define NS 8            // one split per page
#define TPS 256         // tokens per split
#define NGROUP (BATCH * NUM_KV)   // 128 (b,kvh) groups
#define QSCALE 0.08838834764831845f

// ws layout: [NGROUP int counters][pad to 512B] then per (b,kvh,split):
//   [4 M][4 l][4*128 acc] = 520 floats
#define WS_STRIDE 520
#define PART_OFF 128    // float offset of partials (128 ints = 512 B)

__global__ __launch_bounds__(256) void pa_fused(
    const float* __restrict__ q,
    const float* __restrict__ knew,
    const float* __restrict__ vnew,
    const float* __restrict__ kc,
    const float* __restrict__ vc,
    const int* __restrict__ block_tables,
    const int* __restrict__ context_lens,
    float* __restrict__ ws,
    float* __restrict__ out)
{
  // split-major ordering: consecutive block ids span different sequences
  int blk = blockIdx.x;
  int split = blk >> 7;           // 0..7
  int grp = blk & 127;            // b*8+kvh
  int b = grp >> 3;
  int kvh = grp & 7;
  int ctx = context_lens[b];
  int start = split * TPS;
  if (start >= ctx) return;            // uniform over block; inactive blocks don't count
  int n = min(TPS, ctx - start);
  int ns_act = (ctx + TPS - 1) >> 8;   // number of active splits for this group
  int page = block_tables[b * MAXB + split];
  int pbase = page * PAGE;

  int tid = threadIdx.x;
  int w = tid >> 6;       // wave 0..3
  int lane = tid & 63;
  int grp16 = lane >> 4;  // 16-lane token group
  int j = lane & 15;      // lane j owns dims [j*4,j*4+4) and [64+j*4,...)
  int tb = w * 4 + grp16; // token slot within one block iteration (16 tokens/iter)

  int* cnt = (int*)ws;
  float* part = ws + PART_OFF;

  __shared__ float4 s_pv[TPS];        // scores then p, 4 heads packed per token
  __shared__ float s_redM[4][GQ];
  __shared__ float s_redL[4][GQ];
  __shared__ float s_acc[4][GQ][HD];
  __shared__ int s_old;

  // q for this kv head's 4 query heads, pre-scaled, in the lane's dim layout
  float qr[GQ][8];
  #pragma unroll
  for (int g = 0; g < GQ; ++g) {
    const float* qp = q + ((size_t)(b * NUM_HEADS + kvh * GQ + g)) * HD;
    float4 a = *(const float4*)(qp + j * 4);
    float4 c = *(const float4*)(qp + 64 + j * 4);
    qr[g][0]=a.x*QSCALE; qr[g][1]=a.y*QSCALE; qr[g][2]=a.z*QSCALE; qr[g][3]=a.w*QSCALE;
    qr[g][4]=c.x*QSCALE; qr[g][5]=c.y*QSCALE; qr[g][6]=c.z*QSCALE; qr[g][7]=c.w*QSCALE;
  }

  const float* knew_row = knew + (size_t)(b * NUM_KV + kvh) * HD + j * 4;
  const float* vnew_row = vnew + (size_t)(b * NUM_KV + kvh) * HD + j * 4;
  size_t base_off = ((size_t)pbase * NUM_KV + kvh) * HD + j * 4;
  const float* kbase = kc + base_off;
  const float* vbase = vc + base_off;
  int newpos = ctx - 1 - start;        // in [0,n) iff this split holds the new token

  int iters = (n + 15) >> 4;

  // ---------- phase 1: all scores of the split ----------
  #pragma unroll 2
  for (int i = 0; i < iters; ++i) {
    int tl = tb + i * 16;
    int tlc = (tl < n) ? tl : 0;       // pad lanes re-read token 0 (L1 hit), masked later
    const float* krow = (tlc == newpos) ? knew_row
                                        : kbase + (size_t)tlc * (NUM_KV * HD);
    float4 k0 = *(const float4*)(krow);
    float4 k1 = *(const float4*)(krow + 64);
    float kk[8] = {k0.x,k0.y,k0.z,k0.w,k1.x,k1.y,k1.z,k1.w};
    float s0 = 0.f, s1 = 0.f, s2 = 0.f, s3 = 0.f;
    #pragma unroll
    for (int e = 0; e < 8; ++e) {
      s0 += qr[0][e] * kk[e];
      s1 += qr[1][e] * kk[e];
      s2 += qr[2][e] * kk[e];
      s3 += qr[3][e] * kk[e];
    }
    #pragma unroll
    for (int mask = 1; mask <= 8; mask <<= 1) {
      s0 += __shfl_xor(s0, mask);
      s1 += __shfl_xor(s1, mask);
      s2 += __shfl_xor(s2, mask);
      s3 += __shfl_xor(s3, mask);
    }
    if (j < 4) {
      float val = (j == 0) ? s0 : (j == 1) ? s1 : (j == 2) ? s2 : s3;
      ((float*)&s_pv[tl])[j] = val;    // garbage at tl>=n masked in phase 2
    }
  }
  __syncthreads();

  // ---------- phase 2: block-wide max, exp, sum (token t = tid) ----------
  float4 sc = s_pv[tid];
  bool valid = tid < n;
  float sv0 = valid ? sc.x : -1e30f;
  float sv1 = valid ? sc.y : -1e30f;
  float sv2 = valid ? sc.z : -1e30f;
  float sv3 = valid ? sc.w : -1e30f;
  float m0 = sv0, m1 = sv1, m2 = sv2, m3 = sv3;
  #pragma unroll
  for (int mask = 1; mask <= 32; mask <<= 1) {
    m0 = fmaxf(m0, __shfl_xor(m0, mask));
    m1 = fmaxf(m1, __shfl_xor(m1, mask));
    m2 = fmaxf(m2, __shfl_xor(m2, mask));
    m3 = fmaxf(m3, __shfl_xor(m3, mask));
  }
  if (lane == 0) {
    s_redM[w][0] = m0; s_redM[w][1] = m1; s_redM[w][2] = m2; s_redM[w][3] = m3;
  }
  __syncthreads();
  float Mg[GQ];
  #pragma unroll
  for (int g = 0; g < GQ; ++g)
    Mg[g] = fmaxf(fmaxf(s_redM[0][g], s_redM[1][g]), fmaxf(s_redM[2][g], s_redM[3][g]));
  float4 p4;
  p4.x = __expf(sv0 - Mg[0]);          // invalid t -> exp(-1e30-M) = 0
  p4.y = __expf(sv1 - Mg[1]);
  p4.z = __expf(sv2 - Mg[2]);
  p4.w = __expf(sv3 - Mg[3]);
  s_pv[tid] = p4;
  float l0 = p4.x, l1 = p4.y, l2 = p4.z, l3 = p4.w;
  #pragma unroll
  for (int mask = 1; mask <= 32; mask <<= 1) {
    l0 += __shfl_xor(l0, mask);
    l1 += __shfl_xor(l1, mask);
    l2 += __shfl_xor(l2, mask);
    l3 += __shfl_xor(l3, mask);
  }
  if (lane == 0) {
    s_redL[w][0] = l0; s_redL[w][1] = l1; s_redL[w][2] = l2; s_redL[w][3] = l3;
  }
  __syncthreads();
  float Lg[GQ];
  #pragma unroll
  for (int g = 0; g < GQ; ++g)
    Lg[g] = s_redL[0][g] + s_redL[1][g] + s_redL[2][g] + s_redL[3][g];

  // ---------- phase 3: PV accumulate ----------
  float acc[GQ][8];
  #pragma unroll
  for (int g = 0; g < GQ; ++g)
    #pragma unroll
    for (int e = 0; e < 8; ++e) acc[g][e] = 0.f;

  #pragma unroll 2
  for (int i = 0; i < iters; ++i) {
    int tl = tb + i * 16;
    int tlc = (tl < n) ? tl : 0;
    const float* vrow = (tlc == newpos) ? vnew_row
                                        : vbase + (size_t)tlc * (NUM_KV * HD);
    float4 v0 = *(const float4*)(vrow);
    float4 v1 = *(const float4*)(vrow + 64);
    float vv[8] = {v0.x,v0.y,v0.z,v0.w,v1.x,v1.y,v1.z,v1.w};
    float4 pp = s_pv[tl];              // p == 0 for tl >= n
    #pragma unroll
    for (int e = 0; e < 8; ++e) {
      acc[0][e] += pp.x * vv[e];
      acc[1][e] += pp.y * vv[e];
      acc[2][e] += pp.z * vv[e];
      acc[3][e] += pp.w * vv[e];
    }
  }

  // ---------- phase 4: additive merge + partial write ----------
  #pragma unroll
  for (int g = 0; g < GQ; ++g)
    #pragma unroll
    for (int e = 0; e < 8; ++e) {
      acc[g][e] += __shfl_xor(acc[g][e], 16);
      acc[g][e] += __shfl_xor(acc[g][e], 32);
    }
  if (lane < 16) {
    #pragma unroll
    for (int g = 0; g < GQ; ++g) {
      #pragma unroll
      for (int e = 0; e < 4; ++e) s_acc[w][g][j * 4 + e] = acc[g][e];
      #pragma unroll
      for (int e = 4; e < 8; ++e) s_acc[w][g][64 + j * 4 + e - 4] = acc[g][e];
    }
  }
  __syncthreads();

  float* outp = part + (size_t)(grp * NS + split) * WS_STRIDE;
  #pragma unroll
  for (int idx = tid; idx < GQ * HD; idx += 256) {
    int g = idx >> 7;
    int d = idx & 127;
    float A = s_acc[0][g][d] + s_acc[1][g][d] + s_acc[2][g][d] + s_acc[3][g][d];
    outp[8 + idx] = A;
    if (d == 0) {
      outp[g] = Mg[g];
      outp[GQ + g] = Lg[g];
    }
  }

  // ---------- last-block finisher (device-scope handshake) ----------
  __threadfence();                     // release: partials visible device-wide
  __syncthreads();
  if (tid == 0) s_old = atomicAdd(&cnt[grp], 1);
  __syncthreads();
  if (s_old != ns_act - 1) return;     // not the last block of this group
  __threadfence();                     // acquire: see other splits' partials

  const float* basep = part + (size_t)grp * NS * WS_STRIDE;
  for (int idx = tid; idx < GQ * HD; idx += 256) {
    int g = idx >> 7;
    int d = idx & 127;
    float M = -1e30f;
    for (int s = 0; s < ns_act; ++s) M = fmaxf(M, basep[s * WS_STRIDE + g]);
    float L = 0.f, A = 0.f;
    for (int s = 0; s < ns_act; ++s) {
      float e = __expf(basep[s * WS_STRIDE + g] - M);
      L += basep[s * WS_STRIDE + GQ + g] * e;
      A += basep[s * WS_STRIDE + 8 + idx] * e;
    }
    out[((size_t)(b * NUM_HEADS) + kvh * GQ + g) * HD + d] = A / L;
  }
}

extern "C" void kernel_launch(void* const* d_in, const int* in_sizes, int n_in,
                              void* d_out, int out_size, void* d_ws, size_t ws_size,
                              hipStream_t stream) {
  const float* q  = (const float*)d_in[0];
  const float* k  = (const float*)d_in[1];
  const float* v  = (const float*)d_in[2];
  const float* kc = (const float*)d_in[3];
  const float* vc = (const float*)d_in[4];
  const int* block_tables = (const int*)d_in[5];
  const int* context_lens = (const int*)d_in[6];
  // d_in[7] = slot_mapping: not needed (new-token position derived from context_lens)

  float* ws = (float*)d_ws;
  float* out = (float*)d_out;

  // zero the per-group arrival counters (captured into the graph, runs每 replay)
  hipMemsetAsync(d_ws, 0, NGROUP * sizeof(int), stream);
  pa_fused<<<BATCH * NUM_KV * NS, 256, 0, stream>>>(
      q, k, v, kc, vc, block_tables, context_lens, ws, out);
}

// Round 8
// 39.588 us; speedup vs baseline: 3.2439x; 3.2439x over previous
//
#include <hip/hip_runtime.h>

#define BATCH 16
#define NUM_HEADS 32
#define NUM_KV 8
#define GQ 4            // query heads per kv head
#define HD 128
#define PAGE 256        // cache block size
#define MAXB 8
#define NS 8            // one split per page
#define TPS 256         // tokens per split
#define QSCALE 0.08838834764831845f

// ws layout per (b,kvh,split): [4 M][4 l][4*128 acc] = 520 floats
#define WS_STRIDE 520

__global__ __launch_bounds__(256) void pa_partial(
    const float* __restrict__ q,
    const float* __restrict__ knew,
    const float* __restrict__ vnew,
    const float* __restrict__ kc,
    const float* __restrict__ vc,
    const int* __restrict__ block_tables,
    const int* __restrict__ context_lens,
    float* __restrict__ ws)
{
  // Stratified decode: co-resident blocks {i, i+256, i+512, i+768} get
  // 4 DIFFERENT sequences and splits {s, s+2, s+4, s+6} -> per-CU work ~ mean.
  int blk = blockIdx.x;
  int t = blk >> 8;               // 2 bits
  int r = blk & 255;
  int b = (t << 2) | (r & 3);
  int kvh = (r >> 2) & 7;
  int split = ((r >> 5) + (t << 1)) & 7;

  int ctx = context_lens[b];
  int start = split * TPS;
  if (start >= ctx) return;            // uniform over block
  int n = min(TPS, ctx - start);
  int page = block_tables[b * MAXB + split];
  int pbase = page * PAGE;

  int tid = threadIdx.x;
  int w = tid >> 6;       // wave 0..3
  int lane = tid & 63;
  int grp = lane >> 4;    // 16-lane token group
  int j = lane & 15;      // lane j owns dims [j*4,j*4+4) and [64+j*4,...)
  int tb = w * 4 + grp;   // token slot within one block iteration (16 tokens/iter)

  __shared__ float4 s_pv[TPS];        // scores then p, 4 heads packed per token
  __shared__ float s_redM[4][GQ];
  __shared__ float s_redL[4][GQ];
  __shared__ float s_acc[4][GQ][HD];

  // q for this kv head's 4 query heads, pre-scaled, in the lane's dim layout
  float qr[GQ][8];
  #pragma unroll
  for (int g = 0; g < GQ; ++g) {
    const float* qp = q + ((size_t)(b * NUM_HEADS + kvh * GQ + g)) * HD;
    float4 a = *(const float4*)(qp + j * 4);
    float4 c = *(const float4*)(qp + 64 + j * 4);
    qr[g][0]=a.x*QSCALE; qr[g][1]=a.y*QSCALE; qr[g][2]=a.z*QSCALE; qr[g][3]=a.w*QSCALE;
    qr[g][4]=c.x*QSCALE; qr[g][5]=c.y*QSCALE; qr[g][6]=c.z*QSCALE; qr[g][7]=c.w*QSCALE;
  }

  const float* knew_row = knew + (size_t)(b * NUM_KV + kvh) * HD + j * 4;
  const float* vnew_row = vnew + (size_t)(b * NUM_KV + kvh) * HD + j * 4;
  size_t base_off = ((size_t)pbase * NUM_KV + kvh) * HD + j * 4;
  const float* kbase = kc + base_off;
  const float* vbase = vc + base_off;
  int newpos = ctx - 1 - start;        // in [0,n) iff this split holds the new token

  int iters = (n + 15) >> 4;

  // ---------- phase 1: all scores of the split ----------
  #pragma unroll 2
  for (int i = 0; i < iters; ++i) {
    int tl = tb + i * 16;
    int tlc = (tl < n) ? tl : 0;       // pad lanes re-read token 0 (L1 hit), masked later
    const float* krow = (tlc == newpos) ? knew_row
                                        : kbase + (size_t)tlc * (NUM_KV * HD);
    float4 k0 = *(const float4*)(krow);
    float4 k1 = *(const float4*)(krow + 64);
    float kk[8] = {k0.x,k0.y,k0.z,k0.w,k1.x,k1.y,k1.z,k1.w};
    float s0 = 0.f, s1 = 0.f, s2 = 0.f, s3 = 0.f;
    #pragma unroll
    for (int e = 0; e < 8; ++e) {
      s0 += qr[0][e] * kk[e];
      s1 += qr[1][e] * kk[e];
      s2 += qr[2][e] * kk[e];
      s3 += qr[3][e] * kk[e];
    }
    #pragma unroll
    for (int mask = 1; mask <= 8; mask <<= 1) {
      s0 += __shfl_xor(s0, mask);
      s1 += __shfl_xor(s1, mask);
      s2 += __shfl_xor(s2, mask);
      s3 += __shfl_xor(s3, mask);
    }
    if (j < 4) {
      float val = (j == 0) ? s0 : (j == 1) ? s1 : (j == 2) ? s2 : s3;
      ((float*)&s_pv[tl])[j] = val;    // garbage at tl>=n masked in phase 2
    }
  }
  __syncthreads();

  // ---------- phase 2: block-wide max, exp, sum (token t = tid) ----------
  float4 sc = s_pv[tid];
  bool valid = tid < n;
  float sv0 = valid ? sc.x : -1e30f;
  float sv1 = valid ? sc.y : -1e30f;
  float sv2 = valid ? sc.z : -1e30f;
  float sv3 = valid ? sc.w : -1e30f;
  float m0 = sv0, m1 = sv1, m2 = sv2, m3 = sv3;
  #pragma unroll
  for (int mask = 1; mask <= 32; mask <<= 1) {
    m0 = fmaxf(m0, __shfl_xor(m0, mask));
    m1 = fmaxf(m1, __shfl_xor(m1, mask));
    m2 = fmaxf(m2, __shfl_xor(m2, mask));
    m3 = fmaxf(m3, __shfl_xor(m3, mask));
  }
  if (lane == 0) {
    s_redM[w][0] = m0; s_redM[w][1] = m1; s_redM[w][2] = m2; s_redM[w][3] = m3;
  }
  __syncthreads();
  float Mg[GQ];
  #pragma unroll
  for (int g = 0; g < GQ; ++g)
    Mg[g] = fmaxf(fmaxf(s_redM[0][g], s_redM[1][g]), fmaxf(s_redM[2][g], s_redM[3][g]));
  float4 p4;
  p4.x = __expf(sv0 - Mg[0]);          // invalid t -> exp(-1e30-M) = 0
  p4.y = __expf(sv1 - Mg[1]);
  p4.z = __expf(sv2 - Mg[2]);
  p4.w = __expf(sv3 - Mg[3]);
  s_pv[tid] = p4;
  float l0 = p4.x, l1 = p4.y, l2 = p4.z, l3 = p4.w;
  #pragma unroll
  for (int mask = 1; mask <= 32; mask <<= 1) {
    l0 += __shfl_xor(l0, mask);
    l1 += __shfl_xor(l1, mask);
    l2 += __shfl_xor(l2, mask);
    l3 += __shfl_xor(l3, mask);
  }
  if (lane == 0) {
    s_redL[w][0] = l0; s_redL[w][1] = l1; s_redL[w][2] = l2; s_redL[w][3] = l3;
  }
  __syncthreads();
  float Lg[GQ];
  #pragma unroll
  for (int g = 0; g < GQ; ++g)
    Lg[g] = s_redL[0][g] + s_redL[1][g] + s_redL[2][g] + s_redL[3][g];

  // ---------- phase 3: PV accumulate ----------
  float acc[GQ][8];
  #pragma unroll
  for (int g = 0; g < GQ; ++g)
    #pragma unroll
    for (int e = 0; e < 8; ++e) acc[g][e] = 0.f;

  #pragma unroll 2
  for (int i = 0; i < iters; ++i) {
    int tl = tb + i * 16;
    int tlc = (tl < n) ? tl : 0;
    const float* vrow = (tlc == newpos) ? vnew_row
                                        : vbase + (size_t)tlc * (NUM_KV * HD);
    float4 v0 = *(const float4*)(vrow);
    float4 v1 = *(const float4*)(vrow + 64);
    float vv[8] = {v0.x,v0.y,v0.z,v0.w,v1.x,v1.y,v1.z,v1.w};
    float4 pp = s_pv[tl];              // p == 0 for tl >= n
    #pragma unroll
    for (int e = 0; e < 8; ++e) {
      acc[0][e] += pp.x * vv[e];
      acc[1][e] += pp.y * vv[e];
      acc[2][e] += pp.z * vv[e];
      acc[3][e] += pp.w * vv[e];
    }
  }

  // ---------- phase 4: additive merge across the 16 token-groups ----------
  #pragma unroll
  for (int g = 0; g < GQ; ++g)
    #pragma unroll
    for (int e = 0; e < 8; ++e) {
      acc[g][e] += __shfl_xor(acc[g][e], 16);
      acc[g][e] += __shfl_xor(acc[g][e], 32);
    }
  if (lane < 16) {
    #pragma unroll
    for (int g = 0; g < GQ; ++g) {
      #pragma unroll
      for (int e = 0; e < 4; ++e) s_acc[w][g][j * 4 + e] = acc[g][e];
      #pragma unroll
      for (int e = 4; e < 8; ++e) s_acc[w][g][64 + j * 4 + e - 4] = acc[g][e];
    }
  }
  __syncthreads();

  float* outp = ws + (size_t)(((b * NUM_KV) + kvh) * NS + split) * WS_STRIDE;
  #pragma unroll
  for (int idx = tid; idx < GQ * HD; idx += 256) {
    int g = idx >> 7;
    int d = idx & 127;
    float A = s_acc[0][g][d] + s_acc[1][g][d] + s_acc[2][g][d] + s_acc[3][g][d];
    outp[8 + idx] = A;
    if (d == 0) {
      outp[g] = Mg[g];
      outp[GQ + g] = Lg[g];
    }
  }
}

__global__ __launch_bounds__(128) void pa_reduce(
    const float* __restrict__ ws,
    const int* __restrict__ context_lens,
    float* __restrict__ out)
{
  int blk = blockIdx.x;     // (b, kv, g)
  int g  = blk & 3;
  int kv = (blk >> 2) & 7;
  int b  = blk >> 5;
  int d  = threadIdx.x;
  int ctx = context_lens[b];
  int ns = (ctx + TPS - 1) / TPS;
  const float* base = ws + (size_t)((b * NUM_KV + kv) * NS) * WS_STRIDE;

  float M = -1e30f;
  for (int s = 0; s < ns; ++s) M = fmaxf(M, base[s * WS_STRIDE + g]);
  float Lsum = 0.f, A = 0.f;
  for (int s = 0; s < ns; ++s) {
    float e = __expf(base[s * WS_STRIDE + g] - M);
    Lsum += base[s * WS_STRIDE + GQ + g] * e;
    A    += base[s * WS_STRIDE + 8 + g * HD + d] * e;
  }
  out[((size_t)(b * NUM_HEADS) + kv * GQ + g) * HD + d] = A / Lsum;
}

extern "C" void kernel_launch(void* const* d_in, const int* in_sizes, int n_in,
                              void* d_out, int out_size, void* d_ws, size_t ws_size,
                              hipStream_t stream) {
  const float* q  = (const float*)d_in[0];
  const float* k  = (const float*)d_in[1];
  const float* v  = (const float*)d_in[2];
  const float* kc = (const float*)d_in[3];
  const float* vc = (const float*)d_in[4];
  const int* block_tables = (const int*)d_in[5];
  const int* context_lens = (const int*)d_in[6];
  // d_in[7] = slot_mapping: not needed (new-token position derived from context_lens)

  float* ws = (float*)d_ws;
  float* out = (float*)d_out;

  pa_partial<<<BATCH * NUM_KV * NS, 256, 0, stream>>>(
      q, k, v, kc, vc, block_tables, context_lens, ws);
  pa_reduce<<<BATCH * NUM_KV * GQ, 128, 0, stream>>>(ws, context_lens, out);
}